// Round 5
// baseline (131.473 us; speedup 1.0000x reference)
//
#include <hip/hip_runtime.h>

#define B_   128
#define L_   26
#define C1_  128
#define C2_  64
#define K1_  7
#define K2_  5
#define NPOS 25
#define FEAT (L_*C2_)            // 1664
#define NPAIR (NPOS*(NPOS+1)/2)  // 325

// ---------------------------------------------------------------------------
// Kernel A: one-hot -> conv1(k7,relu) -> conv2(k5,relu) -> featT[u][b]
// grid = 128 b * 4 c2-tiles(16 c2); block = 256 (4 waves)
// w1 (14KB) AND w2 tile (40KB) staged in LDS -> hot loops are LDS-only.
// LDS total ~70.8KB -> exactly 2 blocks/CU on all 256 CUs.
// ---------------------------------------------------------------------------
__global__ __launch_bounds__(256) void conv_kernel(
    const int*   __restrict__ x,
    const float* __restrict__ w1, const float* __restrict__ b1,
    const float* __restrict__ w2, const float* __restrict__ b2,
    float* __restrict__ featT)
{
    __shared__ float h1s[C1_][L_ + 4];      // [c1][pos+2], pads zero
    __shared__ float w2s[16*C1_*K2_];       // 10240 floats = 40KB
    __shared__ float w1s[C1_*4*K1_];        // 3584 floats = 14KB
    __shared__ int   xs[L_];

    const int bid = blockIdx.x;
    const int b   = bid >> 2;
    const int c2t = bid & 3;
    const int t   = threadIdx.x;

    if (t < L_)  xs[t] = x[b*L_ + t];
    if (t < C1_) { h1s[t][0] = 0.f; h1s[t][1] = 0.f;
                   h1s[t][L_+2] = 0.f; h1s[t][L_+3] = 0.f; }

    // stage w1: 3584 contiguous floats, coalesced
    for (int i = t; i < C1_*4*K1_; i += 256) w1s[i] = w1[i];

    // stage w2 slice for this block's 16 c2: 10240 contiguous floats, float4
    {
        const float* src = w2 + c2t*16*C1_*K2_;
        #pragma unroll
        for (int i = 0; i < 10; ++i) {
            const int idx = t*4 + i*1024;
            *(float4*)&w2s[idx] = *(const float4*)&src[idx];
        }
    }
    __syncthreads();

    // stage 1: h1[c1][l] = relu(b1 + sum_k w1[c1][x[l+k-3]][k])  (LDS only)
    for (int idx = t; idx < C1_*L_; idx += 256) {
        const int c1 = idx / L_;
        const int l  = idx - c1*L_;
        float s = b1[c1];
        const float* w1r = &w1s[c1*4*K1_];
        #pragma unroll
        for (int k = 0; k < K1_; ++k) {
            const int pos = l + k - 3;
            if (pos >= 0 && pos < L_) s += w1r[xs[pos]*K1_ + k];
        }
        h1s[c1][l+2] = fmaxf(s, 0.f);
    }
    __syncthreads();

    // stage 2: 16 c2 x 26 l outputs, LDS only
    for (int o = t; o < 16*L_; o += 256) {
        const int l   = o % L_;
        const int c2i = o / L_;
        const int c2  = c2t*16 + c2i;
        float acc0 = b2[c2], acc1 = 0.f;
        const float* wbase = &w2s[c2i*C1_*K2_];
        for (int c1 = 0; c1 < C1_; c1 += 2) {
            const float* wr0 = wbase + c1*K2_;
            const float* hr0 = &h1s[c1][l];
            acc0 += wr0[0]*hr0[0] + wr0[1]*hr0[1] + wr0[2]*hr0[2]
                  + wr0[3]*hr0[3] + wr0[4]*hr0[4];
            const float* wr1 = wr0 + K2_;
            const float* hr1 = &h1s[c1+1][l];
            acc1 += wr1[0]*hr1[0] + wr1[1]*hr1[1] + wr1[2]*hr1[2]
                  + wr1[3]*hr1[3] + wr1[4]*hr1[4];
        }
        featT[(l*C2_ + c2)*B_ + b] = fmaxf(acc0 + acc1, 0.f);
    }
}

// ---------------------------------------------------------------------------
// Kernel B: blocks 0..649: pair (i,j) = bid>>1, p-half = bid&1:
//             out[b] += f_i(b)[32 rows]^T W_half f_j(b)
//           block 650: first-order + constants
// W half (8KB) staged in LDS coalesced; consumed as float4 broadcast.
// block = 512: lane b = t&127, quarter = t>>7 owns 8 p-rows.
// ---------------------------------------------------------------------------
__global__ __launch_bounds__(512) void reg_kernel(
    const float* __restrict__ featT,
    const float* __restrict__ rw, const float* __restrict__ rb,
    float* __restrict__ out)
{
    __shared__ float ws[32*64];   // 8KB
    __shared__ float red[B_];
    const int t = threadIdx.x;
    const int b = t & 127;
    const int quarter = t >> 7;
    const int bid = blockIdx.x;

    if (t < B_) red[t] = 0.f;

    float acc = 0.f;

    if (bid == 2*NPAIR) {                    // first order + const
        __syncthreads();
        const int u0 = quarter * (FEAT/4);
        for (int u = u0; u < u0 + FEAT/4; ++u)
            acc += featT[u*B_ + b] * rw[1 + u];
        if (quarter == 0) acc += rw[0] + rb[0];
    } else {
        const int pid  = bid >> 1;
        const int half = bid & 1;
        // decode (i,j) from pid
        int i = 0, r = pid;
        while (r >= NPOS - i) { r -= NPOS - i; ++i; }
        const int j = i + 1 + r;

        const int stride = (NPOS - i) * 64;
        const int base   = 1 + FEAT + 4096*(NPOS*i - (i*(i-1))/2)
                         + (j - i - 1)*64 + half*32*stride;

        // stage 32 W rows: ws[pl*64+q] = rw[base + pl*stride + q]
        #pragma unroll
        for (int k = 0; k < 4; ++k) {
            const int idx = t + k*512;       // 0..2047, q consecutive per lane
            ws[idx] = rw[base + (idx >> 6)*stride + (idx & 63)];
        }
        __syncthreads();

        float fj[64];
        #pragma unroll
        for (int q = 0; q < 64; ++q)
            fj[q] = featT[(j*64 + q)*B_ + b];

        const int p0g = half*32 + quarter*8;     // global p base
        const int p0l = quarter*8;               // local row in ws
        float fi[8];
        #pragma unroll
        for (int p = 0; p < 8; ++p)
            fi[p] = featT[(i*64 + p0g + p)*B_ + b];

        #pragma unroll
        for (int p = 0; p < 8; ++p) {
            const float4* wrow = (const float4*)&ws[(p0l + p)*64];
            float s0 = 0.f, s1 = 0.f, s2 = 0.f, s3 = 0.f;
            #pragma unroll
            for (int qq = 0; qq < 16; ++qq) {
                const float4 w = wrow[qq];
                s0 += w.x*fj[qq*4+0];
                s1 += w.y*fj[qq*4+1];
                s2 += w.z*fj[qq*4+2];
                s3 += w.w*fj[qq*4+3];
            }
            acc += fi[p] * ((s0+s1)+(s2+s3));
        }
    }

    atomicAdd(&red[b], acc);
    __syncthreads();
    if (t < B_) atomicAdd(&out[t], red[t]);
}

// ---------------------------------------------------------------------------
extern "C" void kernel_launch(void* const* d_in, const int* in_sizes, int n_in,
                              void* d_out, int out_size, void* d_ws, size_t ws_size,
                              hipStream_t stream)
{
    const int*   x  = (const int*)  d_in[0];
    const float* w1 = (const float*)d_in[1];
    const float* b1 = (const float*)d_in[2];
    const float* w2 = (const float*)d_in[3];
    const float* b2 = (const float*)d_in[4];
    const float* rw = (const float*)d_in[5];
    const float* rb = (const float*)d_in[6];
    float* out   = (float*)d_out;
    float* featT = (float*)d_ws;            // 1664*128*4 = 852 KB

    hipMemsetAsync(out, 0, B_*sizeof(float), stream);
    conv_kernel<<<dim3(512), dim3(256), 0, stream>>>(x, w1, b1, w2, b2, featT);
    reg_kernel <<<dim3(2*NPAIR+1), dim3(512), 0, stream>>>(featT, rw, rb, out);
}

// Round 6
// 131.363 us; speedup vs baseline: 1.0008x; 1.0008x over previous
//
#include <hip/hip_runtime.h>

#define B_   128
#define L_   26
#define C1_  128
#define C2_  64
#define K1_  7
#define K2_  5
#define NPOS 25
#define FEAT (L_*C2_)            // 1664
#define NPAIR (NPOS*(NPOS+1)/2)  // 325
#define NSLICE 16                // redbuf slices to spread atomic contention

// h1s: [row][c1], row = pos+2 (rows 0,1,28,29 are zero pads), stride 132
// w2s: [c2i][k][c1], per-c2i stride 644 (pad +4 -> 2-way bank alias only)
#define HROW 132
#define WROW 644

// ---------------------------------------------------------------------------
// Kernel A: one-hot -> conv1(k7,relu) -> conv2(k5,relu) -> featT[b][u]
// grid = 128 b * 4 c2-tiles(16 c2); block = 256 (4 waves)
// Stage 2 is all float4 LDS: per thread 2 outputs (l0,l1=2lg,2lg+1),
// inner loop reads w (b128, shared across l) and h rows (b128, 16-way
// broadcast across c2i lanes). 480 b128 reads / 1280 FMA per thread.
// LDS ~71.5KB -> 2 blocks/CU.
// ---------------------------------------------------------------------------
__global__ __launch_bounds__(256) void conv_kernel(
    const int*   __restrict__ x,
    const float* __restrict__ w1, const float* __restrict__ b1,
    const float* __restrict__ w2, const float* __restrict__ b2,
    float* __restrict__ featT)
{
    __shared__ float h1s[30*HROW];          // 15840B
    __shared__ float w2s[16*WROW];          // 41216B
    __shared__ float w1s[C1_*4*K1_];        // 14336B
    __shared__ int   xs[L_];

    const int bid = blockIdx.x;
    const int b   = bid >> 2;
    const int c2t = bid & 3;
    const int t   = threadIdx.x;

    if (t < L_) xs[t] = x[b*L_ + t];
    // zero pad rows 0,1,28,29
    if (t < HROW) { h1s[0*HROW+t] = 0.f; h1s[1*HROW+t] = 0.f;
                    h1s[28*HROW+t] = 0.f; h1s[29*HROW+t] = 0.f; }

    // stage w1 (contiguous, coalesced)
    for (int i = t; i < C1_*4*K1_; i += 256) w1s[i] = w1[i];

    // stage w2 slice transposed: global [c2][c1][k] -> w2s[c2i][k][c1]
    {
        const float* src = w2 + c2t*16*C1_*K2_;
        for (int idx = t; idx < 16*C1_*K2_; idx += 256) {
            const int c2i = idx / (C1_*K2_);
            const int rem = idx - c2i*(C1_*K2_);
            const int c1  = rem / K2_;
            const int k   = rem - c1*K2_;
            w2s[c2i*WROW + k*C1_ + c1] = src[idx];
        }
    }
    __syncthreads();

    // stage 1: h1s[l+2][c1] = relu(b1 + sum_k w1[c1][x[l+k-3]][k])
    for (int idx = t; idx < C1_*L_; idx += 256) {
        const int c1 = idx & 127;
        const int l  = idx >> 7;
        float s = b1[c1];
        const float* w1r = &w1s[c1*4*K1_];
        #pragma unroll
        for (int k = 0; k < K1_; ++k) {
            const int pos = l + k - 3;
            if (pos >= 0 && pos < L_) s += w1r[xs[pos]*K1_ + k];
        }
        h1s[(l+2)*HROW + c1] = fmaxf(s, 0.f);
    }
    __syncthreads();

    // stage 2: thread (c2i = t&15, lg = t>>4 in 0..12) -> outputs l0=2lg, l1=2lg+1
    if (t < 16*13) {
        const int c2i = t & 15;
        const int lg  = t >> 4;
        const int l0  = 2*lg, l1 = 2*lg + 1;
        float a0 = 0.f, a1 = 0.f, a2 = 0.f, a3 = 0.f;
        #pragma unroll
        for (int k = 0; k < K2_; ++k) {
            const float4* wrow = (const float4*)&w2s[c2i*WROW + k*C1_];
            const float4* h0r  = (const float4*)&h1s[(l0 + k)*HROW];
            const float4* h1r  = (const float4*)&h1s[(l1 + k)*HROW];
            #pragma unroll
            for (int cq = 0; cq < 32; cq += 2) {
                const float4 w0 = wrow[cq],  w1v = wrow[cq+1];
                const float4 x0 = h0r[cq],   x1 = h0r[cq+1];
                const float4 y0 = h1r[cq],   y1 = h1r[cq+1];
                a0 += w0.x*x0.x + w0.y*x0.y + w0.z*x0.z + w0.w*x0.w;
                a1 += w1v.x*x1.x + w1v.y*x1.y + w1v.z*x1.z + w1v.w*x1.w;
                a2 += w0.x*y0.x + w0.y*y0.y + w0.z*y0.z + w0.w*y0.w;
                a3 += w1v.x*y1.x + w1v.y*y1.y + w1v.z*y1.z + w1v.w*y1.w;
            }
        }
        const int   c2  = c2t*16 + c2i;
        const float bb  = b2[c2];
        featT[b*FEAT + l0*C2_ + c2] = fmaxf(a0 + a1 + bb, 0.f);
        featT[b*FEAT + l1*C2_ + c2] = fmaxf(a2 + a3 + bb, 0.f);
    }
}

// ---------------------------------------------------------------------------
// Kernel B: blocks 0..324: pair (i,j): red[slice][b] += f_i(b)^T W_ij f_j(b)
//           block 325: first-order + constants
// featT is [b][u]: fj = 16 contiguous float4 per lane, fi = 4.
// W_ij staged in LDS (16KB, coalesced), consumed as broadcast float4.
// Atomics spread over NSLICE redbuf slices (avoids 2-line serialization).
// ---------------------------------------------------------------------------
__global__ __launch_bounds__(512) void reg_kernel(
    const float* __restrict__ featT,
    const float* __restrict__ rw, const float* __restrict__ rb,
    float* __restrict__ redbuf)
{
    __shared__ float ws[64*64];   // 16KB
    __shared__ float red[B_];
    const int t = threadIdx.x;
    const int b = t & 127;
    const int quarter = t >> 7;
    const int bid = blockIdx.x;

    if (t < B_) red[t] = 0.f;

    float acc = 0.f;

    if (bid == NPAIR) {                      // first order + const
        __syncthreads();
        const int u0 = quarter * (FEAT/4);
        const float4* fp = (const float4*)&featT[b*FEAT + u0];
        for (int q = 0; q < FEAT/16; ++q) {  // 104 float4
            const float4 f = fp[q];
            const int u = u0 + q*4;
            acc += f.x*rw[1+u] + f.y*rw[2+u] + f.z*rw[3+u] + f.w*rw[4+u];
        }
        if (quarter == 0) acc += rw[0] + rb[0];
    } else {
        int i = 0, r = bid;
        while (r >= NPOS - i) { r -= NPOS - i; ++i; }
        const int j = i + 1 + r;

        const int stride = (NPOS - i) * 64;
        const int base   = 1 + FEAT + 4096*(NPOS*i - (i*(i-1))/2)
                         + (j - i - 1)*64;

        // stage W_ij rows into ws (coalesced over q)
        #pragma unroll
        for (int k = 0; k < 8; ++k) {
            const int idx = t + k*512;
            ws[idx] = rw[base + (idx >> 6)*stride + (idx & 63)];
        }
        __syncthreads();

        // fj: 16 contiguous float4 per lane
        float4 fj[16];
        const float4* fjp = (const float4*)&featT[b*FEAT + j*64];
        #pragma unroll
        for (int q = 0; q < 16; ++q) fj[q] = fjp[q];

        const int p0 = quarter * 16;
        const float4* fip = (const float4*)&featT[b*FEAT + i*64 + p0];

        #pragma unroll
        for (int pq = 0; pq < 4; ++pq) {
            const float4 f = fip[pq];
            const float fiv[4] = {f.x, f.y, f.z, f.w};
            #pragma unroll
            for (int pp = 0; pp < 4; ++pp) {
                const int p = p0 + pq*4 + pp;
                const float4* wrow = (const float4*)&ws[p*64];
                float s0 = 0.f, s1 = 0.f, s2 = 0.f, s3 = 0.f;
                #pragma unroll
                for (int qq = 0; qq < 16; ++qq) {
                    const float4 w = wrow[qq];
                    s0 += w.x*fj[qq].x;
                    s1 += w.y*fj[qq].y;
                    s2 += w.z*fj[qq].z;
                    s3 += w.w*fj[qq].w;
                }
                acc += fiv[pp] * ((s0+s1)+(s2+s3));
            }
        }
    }

    atomicAdd(&red[b], acc);
    __syncthreads();
    if (t < B_)
        atomicAdd(&redbuf[(bid & (NSLICE-1))*B_ + t], red[t]);
}

// ---------------------------------------------------------------------------
// finalize: out[b] = sum over slices
// ---------------------------------------------------------------------------
__global__ __launch_bounds__(128) void fin_kernel(
    const float* __restrict__ redbuf, float* __restrict__ out)
{
    const int b = threadIdx.x;
    float s = 0.f;
    #pragma unroll
    for (int sl = 0; sl < NSLICE; ++sl) s += redbuf[sl*B_ + b];
    out[b] = s;
}

// ---------------------------------------------------------------------------
extern "C" void kernel_launch(void* const* d_in, const int* in_sizes, int n_in,
                              void* d_out, int out_size, void* d_ws, size_t ws_size,
                              hipStream_t stream)
{
    const int*   x  = (const int*)  d_in[0];
    const float* w1 = (const float*)d_in[1];
    const float* b1 = (const float*)d_in[2];
    const float* w2 = (const float*)d_in[3];
    const float* b2 = (const float*)d_in[4];
    const float* rw = (const float*)d_in[5];
    const float* rb = (const float*)d_in[6];
    float* out    = (float*)d_out;
    float* featT  = (float*)d_ws;                       // 128*1664*4 = 851968 B
    float* redbuf = (float*)((char*)d_ws + 851968);     // 16*128*4 = 8192 B

    hipMemsetAsync(redbuf, 0, NSLICE*B_*sizeof(float), stream);
    conv_kernel<<<dim3(512), dim3(256), 0, stream>>>(x, w1, b1, w2, b2, featT);
    reg_kernel <<<dim3(NPAIR+1), dim3(512), 0, stream>>>(featT, rw, rb, redbuf);
    fin_kernel <<<dim3(1), dim3(128), 0, stream>>>(redbuf, out);
}

// Round 7
// 130.354 us; speedup vs baseline: 1.0086x; 1.0077x over previous
//
#include <hip/hip_runtime.h>

#define B_   128
#define L_   26
#define C1_  128
#define C2_  64
#define K1_  7
#define K2_  5
#define NPOS 25
#define FEAT (L_*C2_)            // 1664
#define NPAIR (NPOS*(NPOS+1)/2)  // 325
#define NSLICE 16                // redbuf slices to spread atomic contention

// h1s: [row][c1], row = pos+2 (rows 0,1,28,29 are zero pads), stride 132
// w2s: [c2i][k][c1], per-c2i stride 644 (pad +4 -> 2-way bank alias only)
#define HROW 132
#define WROW 644

// ---------------------------------------------------------------------------
// Kernel A (UNCHANGED from round 6): conv1 -> conv2 -> featT[b][u]
// ---------------------------------------------------------------------------
__global__ __launch_bounds__(256) void conv_kernel(
    const int*   __restrict__ x,
    const float* __restrict__ w1, const float* __restrict__ b1,
    const float* __restrict__ w2, const float* __restrict__ b2,
    float* __restrict__ featT)
{
    __shared__ float h1s[30*HROW];          // 15840B
    __shared__ float w2s[16*WROW];          // 41216B
    __shared__ float w1s[C1_*4*K1_];        // 14336B
    __shared__ int   xs[L_];

    const int bid = blockIdx.x;
    const int b   = bid >> 2;
    const int c2t = bid & 3;
    const int t   = threadIdx.x;

    if (t < L_) xs[t] = x[b*L_ + t];
    if (t < HROW) { h1s[0*HROW+t] = 0.f; h1s[1*HROW+t] = 0.f;
                    h1s[28*HROW+t] = 0.f; h1s[29*HROW+t] = 0.f; }

    for (int i = t; i < C1_*4*K1_; i += 256) w1s[i] = w1[i];

    {
        const float* src = w2 + c2t*16*C1_*K2_;
        for (int idx = t; idx < 16*C1_*K2_; idx += 256) {
            const int c2i = idx / (C1_*K2_);
            const int rem = idx - c2i*(C1_*K2_);
            const int c1  = rem / K2_;
            const int k   = rem - c1*K2_;
            w2s[c2i*WROW + k*C1_ + c1] = src[idx];
        }
    }
    __syncthreads();

    for (int idx = t; idx < C1_*L_; idx += 256) {
        const int c1 = idx & 127;
        const int l  = idx >> 7;
        float s = b1[c1];
        const float* w1r = &w1s[c1*4*K1_];
        #pragma unroll
        for (int k = 0; k < K1_; ++k) {
            const int pos = l + k - 3;
            if (pos >= 0 && pos < L_) s += w1r[xs[pos]*K1_ + k];
        }
        h1s[(l+2)*HROW + c1] = fmaxf(s, 0.f);
    }
    __syncthreads();

    if (t < 16*13) {
        const int c2i = t & 15;
        const int lg  = t >> 4;
        const int l0  = 2*lg, l1 = 2*lg + 1;
        float a0 = 0.f, a1 = 0.f, a2 = 0.f, a3 = 0.f;
        #pragma unroll
        for (int k = 0; k < K2_; ++k) {
            const float4* wrow = (const float4*)&w2s[c2i*WROW + k*C1_];
            const float4* h0r  = (const float4*)&h1s[(l0 + k)*HROW];
            const float4* h1r  = (const float4*)&h1s[(l1 + k)*HROW];
            #pragma unroll
            for (int cq = 0; cq < 32; cq += 2) {
                const float4 w0 = wrow[cq],  w1v = wrow[cq+1];
                const float4 x0 = h0r[cq],   x1 = h0r[cq+1];
                const float4 y0 = h1r[cq],   y1 = h1r[cq+1];
                a0 += w0.x*x0.x + w0.y*x0.y + w0.z*x0.z + w0.w*x0.w;
                a1 += w1v.x*x1.x + w1v.y*x1.y + w1v.z*x1.z + w1v.w*x1.w;
                a2 += w0.x*y0.x + w0.y*y0.y + w0.z*y0.z + w0.w*y0.w;
                a3 += w1v.x*y1.x + w1v.y*y1.y + w1v.z*y1.z + w1v.w*y1.w;
            }
        }
        const int   c2  = c2t*16 + c2i;
        const float bb  = b2[c2];
        featT[b*FEAT + l0*C2_ + c2] = fmaxf(a0 + a1 + bb, 0.f);
        featT[b*FEAT + l1*C2_ + c2] = fmaxf(a2 + a3 + bb, 0.f);
    }
}

// ---------------------------------------------------------------------------
// Kernel B: REGISTER-BOUNDED rewrite (round-6 version spilled fj[16] float4
// -> 256 scratch reloads/thread = the invariant 40us).
// New: sp[16] partials; fj streamed one float4 at a time from L2.
// Per thread: 16 global float4 (L2) + 256 broadcast ds_read_b128 + 1024 FMA.
// ~40 VGPR -> no scratch.
// ---------------------------------------------------------------------------
__global__ __launch_bounds__(512) void reg_kernel(
    const float* __restrict__ featT,
    const float* __restrict__ rw, const float* __restrict__ rb,
    float* __restrict__ redbuf)
{
    __shared__ float ws[64*64];   // 16KB
    __shared__ float red[B_];
    const int t = threadIdx.x;
    const int b = t & 127;
    const int quarter = t >> 7;
    const int bid = blockIdx.x;

    if (t < B_) red[t] = 0.f;

    float acc = 0.f;

    if (bid == NPAIR) {                      // first order + const
        __syncthreads();
        const int u0 = quarter * (FEAT/4);
        const float4* fp = (const float4*)&featT[b*FEAT + u0];
        float a0 = 0.f, a1 = 0.f, a2 = 0.f, a3 = 0.f;
        for (int q = 0; q < FEAT/16; ++q) {  // 104 float4
            const float4 f = fp[q];
            const int u = u0 + q*4;
            a0 += f.x*rw[1+u]; a1 += f.y*rw[2+u];
            a2 += f.z*rw[3+u]; a3 += f.w*rw[4+u];
        }
        acc = (a0+a1)+(a2+a3);
        if (quarter == 0 && b == 0) acc += rw[0] + rb[0];
    } else {
        int i = 0, r = bid;
        while (r >= NPOS - i) { r -= NPOS - i; ++i; }
        const int j = i + 1 + r;

        const int stride = (NPOS - i) * 64;
        const int base   = 1 + FEAT + 4096*(NPOS*i - (i*(i-1))/2)
                         + (j - i - 1)*64;

        // stage W_ij rows into ws (coalesced over q: wave reads one 256B row)
        #pragma unroll
        for (int k = 0; k < 8; ++k) {
            const int idx = t + k*512;
            ws[idx] = rw[base + (idx >> 6)*stride + (idx & 63)];
        }
        __syncthreads();

        const int p0 = quarter * 16;
        float sp[16];
        #pragma unroll
        for (int pp = 0; pp < 16; ++pp) sp[pp] = 0.f;

        const float4* fjp = (const float4*)&featT[b*FEAT + j*64];
        #pragma unroll 4
        for (int qq = 0; qq < 16; ++qq) {
            const float4 f = fjp[qq];                 // L2-hit stream
            #pragma unroll
            for (int pp = 0; pp < 16; ++pp) {         // broadcast LDS rows
                const float4 w = *(const float4*)&ws[(p0 + pp)*64 + qq*4];
                sp[pp] += w.x*f.x + w.y*f.y + w.z*f.z + w.w*f.w;
            }
        }

        const float4* fip = (const float4*)&featT[b*FEAT + i*64 + p0];
        #pragma unroll
        for (int pq = 0; pq < 4; ++pq) {
            const float4 f = fip[pq];
            acc += f.x*sp[4*pq+0] + f.y*sp[4*pq+1]
                 + f.z*sp[4*pq+2] + f.w*sp[4*pq+3];
        }
    }

    atomicAdd(&red[b], acc);
    __syncthreads();
    if (t < B_)
        atomicAdd(&redbuf[(bid & (NSLICE-1))*B_ + t], red[t]);
}

// ---------------------------------------------------------------------------
__global__ __launch_bounds__(128) void fin_kernel(
    const float* __restrict__ redbuf, float* __restrict__ out)
{
    const int b = threadIdx.x;
    float s = 0.f;
    #pragma unroll
    for (int sl = 0; sl < NSLICE; ++sl) s += redbuf[sl*B_ + b];
    out[b] = s;
}

// ---------------------------------------------------------------------------
extern "C" void kernel_launch(void* const* d_in, const int* in_sizes, int n_in,
                              void* d_out, int out_size, void* d_ws, size_t ws_size,
                              hipStream_t stream)
{
    const int*   x  = (const int*)  d_in[0];
    const float* w1 = (const float*)d_in[1];
    const float* b1 = (const float*)d_in[2];
    const float* w2 = (const float*)d_in[3];
    const float* b2 = (const float*)d_in[4];
    const float* rw = (const float*)d_in[5];
    const float* rb = (const float*)d_in[6];
    float* out    = (float*)d_out;
    float* featT  = (float*)d_ws;                       // 128*1664*4 = 851968 B
    float* redbuf = (float*)((char*)d_ws + 851968);     // 16*128*4 = 8192 B

    hipMemsetAsync(redbuf, 0, NSLICE*B_*sizeof(float), stream);
    conv_kernel<<<dim3(512), dim3(256), 0, stream>>>(x, w1, b1, w2, b2, featT);
    reg_kernel <<<dim3(NPAIR+1), dim3(512), 0, stream>>>(featT, rw, rb, redbuf);
    fin_kernel <<<dim3(1), dim3(128), 0, stream>>>(redbuf, out);
}